// Round 6
// baseline (202.228 us; speedup 1.0000x reference)
//
#include <hip/hip_runtime.h>
#include <hip/hip_fp16.h>

// EfficientAttention  B=4, S=4096, D=1024, fp32 in/out.
//   G[b]   = x[b]^T x[b]              (Gram, split-K=4, fp16 partials in d_out)
//   Gh     = (1/32) sum_k parts
//   Ph[b]  = Wv Gh[b] ; KVt[b] = Ph Wk^T + rank-1 bias ; Rt[b] = KVt Wq^T
//   E[b]   = x Rt^T + cv[b]
// Big GEMMs (Gram, E): 256x128 tile, ring-3 LDS, depth-2 prefetch, counted
// vmcnt(6) (T3+T4), setprio around MFMA (T5), raw s_barrier (1 per K-tile).

#define BATCH 4
#define SEQ   4096
#define DM    1024

typedef _Float16 h8 __attribute__((ext_vector_type(8)));
typedef _Float16 h4 __attribute__((ext_vector_type(4)));
typedef float    f4 __attribute__((ext_vector_type(4)));

__device__ inline void gload_lds16(const _Float16* g, _Float16* l) {
    __builtin_amdgcn_global_load_lds(
        (const __attribute__((address_space(1))) void*)g,
        (__attribute__((address_space(3))) void*)l,
        16, 0, 0);
}

// bijective XCD chunk swizzle (gridDim.x % 8 == 0)
__device__ inline int xcd_swz(int bid, int grid) {
    const int q = grid >> 3;
    return (bid & 7) * q + (bid >> 3);
}

// fp32 [Z][R][C] -> fp16 transposed [Z][C][R] (dstT), optionally also row-major fp16.
template<bool WRITE_RM>
__global__ __launch_bounds__(256) void cvt_transpose(
    const float* __restrict__ src, _Float16* __restrict__ dstT,
    _Float16* __restrict__ dstRM, int R, int C)
{
    __shared__ float tile[64][65];
    const long zoff = (long)blockIdx.z * R * C;
    src += zoff; dstT += zoff;
    if (WRITE_RM) dstRM += zoff;
    const int r0 = blockIdx.y * 64;
    const int c0 = blockIdx.x * 64;
    const int t  = threadIdx.x;
    const int tr = t >> 4;
    const int tc = (t & 15) * 4;
    #pragma unroll
    for (int i = 0; i < 4; ++i) {
        const int r = tr + i * 16;
        f4 v = *(const f4*)&src[(long)(r0 + r) * C + c0 + tc];
        tile[r][tc + 0] = v.x; tile[r][tc + 1] = v.y;
        tile[r][tc + 2] = v.z; tile[r][tc + 3] = v.w;
        if (WRITE_RM) {
            h4 h = { (_Float16)v.x, (_Float16)v.y, (_Float16)v.z, (_Float16)v.w };
            *(h4*)&dstRM[(long)(r0 + r) * C + c0 + tc] = h;
        }
    }
    __syncthreads();
    #pragma unroll
    for (int i = 0; i < 4; ++i) {
        const int c = tr + i * 16;
        h4 h = { (_Float16)tile[tc + 0][c], (_Float16)tile[tc + 1][c],
                 (_Float16)tile[tc + 2][c], (_Float16)tile[tc + 3][c] };
        *(h4*)&dstT[(long)(c0 + c) * R + r0 + tc] = h;
    }
}

// Wk, Wv -> fp16 in one launch
__global__ __launch_bounds__(256) void cvt_pair(
    const float* __restrict__ s0, _Float16* __restrict__ d0,
    const float* __restrict__ s1, _Float16* __restrict__ d1)
{
    const int half = blockIdx.x >> 10;
    const long i = ((long)(blockIdx.x & 1023) * 256 + threadIdx.x) * 4;
    const float* s = half ? s1 : s0;
    _Float16*    d = half ? d1 : d0;
    f4 v = *(const f4*)(s + i);
    h4 h = { (_Float16)v.x, (_Float16)v.y, (_Float16)v.z, (_Float16)v.w };
    *(h4*)(d + i) = h;
}

// xs[b*DM + d] = sum_s xt[b][d][s]
__global__ __launch_bounds__(256) void rowsum_xt(
    const _Float16* __restrict__ xt, float* __restrict__ xs)
{
    const int gw   = blockIdx.x * 4 + (threadIdx.x >> 6);
    const int lane = threadIdx.x & 63;
    const _Float16* row = xt + (long)gw * SEQ;
    float s = 0.f;
    #pragma unroll
    for (int i = 0; i < SEQ; i += 512) {
        h8 v = *(const h8*)&row[i + lane * 8];
        #pragma unroll
        for (int j = 0; j < 8; ++j) s += (float)v[j];
    }
    #pragma unroll
    for (int off = 32; off; off >>= 1) s += __shfl_down(s, off);
    if (lane == 0) xs[gw] = s;
}

// dual gemv: u2 = Wv.xs + S*bv ; w = Wk.xs   (dst = u2 base, 8192 floats)
__global__ __launch_bounds__(256) void gemv_dual(
    const _Float16* __restrict__ Wvh, const _Float16* __restrict__ Wkh,
    const float* __restrict__ xs, const float* __restrict__ bv,
    float* __restrict__ dst)
{
    const int gw   = blockIdx.x * 4 + (threadIdx.x >> 6);
    const int half = gw >> 12;
    const int g    = gw & 4095;
    const int b    = g >> 10;
    const int o    = g & 1023;
    const int lane = threadIdx.x & 63;
    const _Float16* wr = (half ? Wkh : Wvh) + (long)o * 1024;
    const float*    v  = xs + b * 1024;
    float s = 0.f;
    #pragma unroll
    for (int i = 0; i < 2; ++i) {
        const int k = i * 512 + lane * 8;
        h8 wv = *(const h8*)&wr[k];
        f4 v0 = *(const f4*)&v[k];
        f4 v1 = *(const f4*)&v[k + 4];
        s += (float)wv[0] * v0.x + (float)wv[1] * v0.y +
             (float)wv[2] * v0.z + (float)wv[3] * v0.w +
             (float)wv[4] * v1.x + (float)wv[5] * v1.y +
             (float)wv[6] * v1.z + (float)wv[7] * v1.w;
    }
    #pragma unroll
    for (int off = 32; off; off >>= 1) s += __shfl_down(s, off);
    if (lane == 0) dst[gw] = s + (half ? 0.f : (float)SEQ * bv[o]);
}

// out[b*1024+o] = sum_k W[b*wZ + o*1024 + k] * vec[k]
__global__ __launch_bounds__(256) void gemv_k1024(
    const _Float16* __restrict__ W, long wZ,
    const float* __restrict__ vec, float* __restrict__ out)
{
    const int gw   = blockIdx.x * 4 + (threadIdx.x >> 6);
    const int b    = gw >> 10;
    const int o    = gw & 1023;
    const int lane = threadIdx.x & 63;
    const _Float16* wr = W + b * wZ + (long)o * 1024;
    float s = 0.f;
    #pragma unroll
    for (int i = 0; i < 2; ++i) {
        const int k = i * 512 + lane * 8;
        h8 wv = *(const h8*)&wr[k];
        f4 v0 = *(const f4*)&vec[k];
        f4 v1 = *(const f4*)&vec[k + 4];
        s += (float)wv[0] * v0.x + (float)wv[1] * v0.y +
             (float)wv[2] * v0.z + (float)wv[3] * v0.w +
             (float)wv[4] * v1.x + (float)wv[5] * v1.y +
             (float)wv[6] * v1.z + (float)wv[7] * v1.w;
    }
    #pragma unroll
    for (int off = 32; off; off >>= 1) s += __shfl_down(s, off);
    if (lane == 0) out[gw] = s;
}

// Gh = (1/32) * sum_{k<4} parts (fp16 partials)
__global__ __launch_bounds__(256) void reduce_gh(
    const _Float16* __restrict__ parts, _Float16* __restrict__ Gh)
{
    const long DD_ = (long)DM * DM;
    const long i = ((long)blockIdx.x * 256 + threadIdx.x) * 8;
    const long b = i >> 20;
    const long r = i & (DD_ - 1);
    const _Float16* p = parts + b * 4 * DD_ + r;
    h8 v0 = *(const h8*)&p[0];
    h8 v1 = *(const h8*)&p[DD_];
    h8 v2 = *(const h8*)&p[2 * DD_];
    h8 v3 = *(const h8*)&p[3 * DD_];
    h8 o;
    #pragma unroll
    for (int j = 0; j < 8; ++j) {
        float s = (float)v0[j] + (float)v1[j] + (float)v2[j] + (float)v3[j];
        o[j] = (_Float16)(s * 0.03125f);
    }
    *(h8*)&Gh[i] = o;
}

// stage one 256x64 A half + 128x64 B tile chunk into an LDS ring buffer (6 issues)
__device__ inline void stage_tile(
    const _Float16* __restrict__ A, const _Float16* __restrict__ B,
    _Float16* as, _Float16* bs, int lda, int ldb,
    int tileM, int tileN, int k0, int tid)
{
    const int srow  = tid >> 3;   // 0..63
    const int sslot = tid & 7;
    #pragma unroll
    for (int i = 0; i < 4; ++i) {
        const int row   = i * 64 + srow;
        const int gslot = sslot ^ (row & 7);
        gload_lds16(&A[(long)(tileM + row) * lda + k0 + gslot * 8],
                    &as[row * 64 + sslot * 8]);
    }
    #pragma unroll
    for (int i = 0; i < 2; ++i) {
        const int row   = i * 64 + srow;
        const int gslot = sslot ^ (row & 7);
        gload_lds16(&B[(long)(tileN + row) * ldb + k0 + gslot * 8],
                    &bs[row * 64 + sslot * 8]);
    }
}

// Pipelined NT GEMM: 256x128 tile, BK=64, 512 thr = 8 waves (4Mx2N), wave 64x64.
// Ring-3 LDS (144KB), depth-2 prefetch, counted vmcnt(6), 1 barrier/K-tile.
// BIAS: 0 none; 1: + bc1[col] per zb.
template<typename OutT, int BIAS>
__global__ __launch_bounds__(512, 1) void gemm_big(
    const _Float16* __restrict__ A, const _Float16* __restrict__ B,
    OutT* __restrict__ C,
    int K, int lda, int ldb, int ldc, int tilesX, int perZ,
    long aZ, long bZ, long cZ, int sk, long aK, long bK,
    const float* __restrict__ bc1, long bc1Z, float alpha)
{
    __shared__ _Float16 As[3][256 * 64];   // 3 x 32 KB
    __shared__ _Float16 Bs[3][128 * 64];   // 3 x 16 KB

    const int L  = xcd_swz(blockIdx.x, gridDim.x);
    const int z  = L / perZ;
    const int r0 = L - z * perZ;
    const int zb = z / sk;
    const int zk = z - zb * sk;
    A += (long)zb * aZ + (long)zk * aK;
    B += (long)zb * bZ + (long)zk * bK;
    C += (long)z * cZ;
    const float* pc1 = (BIAS == 1) ? bc1 + (long)zb * bc1Z : nullptr;

    const int tileM = (r0 / tilesX) * 256;
    const int tileN = (r0 % tilesX) * 128;
    const int tid   = threadIdx.x;
    const int lane  = tid & 63;
    const int wave  = tid >> 6;
    const int wm    = (wave >> 1) * 64;   // 0,64,128,192
    const int wn    = (wave & 1) * 64;    // 0,64

    f4 acc[4][4] = {};
    const int arow = lane & 15;
    const int kg   = lane >> 4;
    const int NT   = K >> 6;

    // prologue: stage tiles 0 and 1; wait for tile 0 (6 of 12 loads may fly)
    stage_tile(A, B, As[0], Bs[0], lda, ldb, tileM, tileN, 0,  tid);
    stage_tile(A, B, As[1], Bs[1], lda, ldb, tileM, tileN, 64, tid);
    asm volatile("s_waitcnt vmcnt(6)" ::: "memory");
    __builtin_amdgcn_sched_barrier(0);
    __builtin_amdgcn_s_barrier();
    asm volatile("" ::: "memory");

    for (int kt = 0; kt < NT; ++kt) {
        _Float16* as = As[kt % 3];
        _Float16* bs = Bs[kt % 3];
        if (kt + 2 < NT)   // prefetch depth 2 into the buffer retired at kt-1
            stage_tile(A, B, As[(kt + 2) % 3], Bs[(kt + 2) % 3],
                       lda, ldb, tileM, tileN, (kt + 2) * 64, tid);

        #pragma unroll
        for (int kk = 0; kk < 64; kk += 32) {
            h8 af[4], bf[4];
            #pragma unroll
            for (int m = 0; m < 4; ++m) {
                const int rr   = wm + m * 16 + arow;
                const int slot = (kk >> 3) + kg;
                af[m] = *(const h8*)&as[rr * 64 + ((slot ^ (rr & 7)) << 3)];
            }
            #pragma unroll
            for (int n = 0; n < 4; ++n) {
                const int rr   = wn + n * 16 + arow;
                const int slot = (kk >> 3) + kg;
                bf[n] = *(const h8*)&bs[rr * 64 + ((slot ^ (rr & 7)) << 3)];
            }
            __builtin_amdgcn_s_setprio(1);
            #pragma unroll
            for (int m = 0; m < 4; ++m)
                #pragma unroll
                for (int n = 0; n < 4; ++n)
                    acc[m][n] = __builtin_amdgcn_mfma_f32_16x16x32_f16(
                        af[m], bf[n], acc[m][n], 0, 0, 0);
            __builtin_amdgcn_s_setprio(0);
        }

        // boundary: kt+1 must be fully landed; keep kt+2's 6 loads in flight
        if (kt + 2 < NT) asm volatile("s_waitcnt vmcnt(6)" ::: "memory");
        else             asm volatile("s_waitcnt vmcnt(0)" ::: "memory");
        __builtin_amdgcn_sched_barrier(0);
        __builtin_amdgcn_s_barrier();
        asm volatile("" ::: "memory");
    }

    #pragma unroll
    for (int m = 0; m < 4; ++m) {
        #pragma unroll
        for (int n = 0; n < 4; ++n) {
            const int col = tileN + wn + n * 16 + arow;
            #pragma unroll
            for (int j = 0; j < 4; ++j) {
                const int row = tileM + wm + m * 16 + (lane >> 4) * 4 + j;
                float v = acc[m][n][j] * alpha;
                if (BIAS == 1) v += pc1[col];
                C[(long)row * ldc + col] = (OutT)v;
            }
        }
    }
}

// 64x64 NT GEMM for the 1024^3 chain.
// BIAS: 0 none; 3: + beta*(bc1[col]*br1[row] + bc2[col]*br2[row])
template<int BIAS>
__global__ __launch_bounds__(256) void gemm64(
    const _Float16* __restrict__ A, const _Float16* __restrict__ B,
    _Float16* __restrict__ C,
    int K, int lda, int ldb, int ldc, int tilesX, int perZ,
    long aZ, long bZ, long cZ,
    const float* __restrict__ bc1, long bc1Z,
    const float* __restrict__ br1, long br1Z,
    const float* __restrict__ bc2, long bc2Z,
    const float* __restrict__ br2, long br2Z,
    float beta)
{
    __shared__ _Float16 As[64 * 64];
    __shared__ _Float16 Bs[64 * 64];

    const int L  = xcd_swz(blockIdx.x, gridDim.x);
    const int z  = L / perZ;
    const int r0 = L - z * perZ;
    A += (long)z * aZ;
    B += (long)z * bZ;
    C += (long)z * cZ;
    const float* pc1 = nullptr; const float* pr1 = nullptr;
    const float* pc2 = nullptr; const float* pr2 = nullptr;
    if (BIAS == 3) {
        pc1 = bc1 + (long)z * bc1Z; pr1 = br1 + (long)z * br1Z;
        pc2 = bc2 + (long)z * bc2Z; pr2 = br2 + (long)z * br2Z;
    }

    const int tileM = (r0 / tilesX) * 64;
    const int tileN = (r0 % tilesX) * 64;
    const int tid   = threadIdx.x;
    const int lane  = tid & 63;
    const int wave  = tid >> 6;
    const int wm    = (wave >> 1) * 32;
    const int wn    = (wave & 1) * 32;
    const int srow  = tid >> 3;
    const int sslot = tid & 7;

    f4 acc[2][2] = {};
    const int arow = lane & 15;
    const int kg   = lane >> 4;

    for (int k0 = 0; k0 < K; k0 += 64) {
        #pragma unroll
        for (int i = 0; i < 2; ++i) {
            const int row   = i * 32 + srow;
            const int gslot = sslot ^ (row & 7);
            gload_lds16(&A[(long)(tileM + row) * lda + k0 + gslot * 8],
                        &As[row * 64 + sslot * 8]);
            gload_lds16(&B[(long)(tileN + row) * ldb + k0 + gslot * 8],
                        &Bs[row * 64 + sslot * 8]);
        }
        __syncthreads();

        #pragma unroll
        for (int kk = 0; kk < 64; kk += 32) {
            h8 af[2], bf[2];
            #pragma unroll
            for (int m = 0; m < 2; ++m) {
                const int rr   = wm + m * 16 + arow;
                const int slot = (kk >> 3) + kg;
                af[m] = *(const h8*)&As[rr * 64 + ((slot ^ (rr & 7)) << 3)];
            }
            #pragma unroll
            for (int n = 0; n < 2; ++n) {
                const int rr   = wn + n * 16 + arow;
                const int slot = (kk >> 3) + kg;
                bf[n] = *(const h8*)&Bs[rr * 64 + ((slot ^ (rr & 7)) << 3)];
            }
            #pragma unroll
            for (int m = 0; m < 2; ++m)
                #pragma unroll
                for (int n = 0; n < 2; ++n)
                    acc[m][n] = __builtin_amdgcn_mfma_f32_16x16x32_f16(
                        af[m], bf[n], acc[m][n], 0, 0, 0);
        }
        __syncthreads();
    }

    #pragma unroll
    for (int m = 0; m < 2; ++m) {
        #pragma unroll
        for (int n = 0; n < 2; ++n) {
            const int col = tileN + wn + n * 16 + arow;
            #pragma unroll
            for (int j = 0; j < 4; ++j) {
                const int row = tileM + wm + m * 16 + (lane >> 4) * 4 + j;
                float v = acc[m][n][j];
                if (BIAS == 3) v += beta * (pc1[col] * pr1[row] + pc2[col] * pr2[row]);
                C[(long)row * ldc + col] = (_Float16)v;
            }
        }
    }
}

extern "C" void kernel_launch(void* const* d_in, const int* in_sizes, int n_in,
                              void* d_out, int out_size, void* d_ws, size_t ws_size,
                              hipStream_t stream)
{
    const float* x  = (const float*)d_in[0];
    const float* Wq = (const float*)d_in[1];
    const float* bq = (const float*)d_in[2];
    const float* Wk = (const float*)d_in[3];
    const float* bk = (const float*)d_in[4];
    const float* Wv = (const float*)d_in[5];
    const float* bv = (const float*)d_in[6];
    float* out = (float*)d_out;

    const long DD = (long)DM * DM;
    const long DS = (long)DM * SEQ;

    char* base = (char*)d_ws;
    _Float16* xh   = (_Float16*)base;
    _Float16* xt   = (_Float16*)(base + 32l * 1024 * 1024);
    _Float16* Gh   = xt;
    _Float16* Ph   = xt + 4l * 1024 * 1024;
    _Float16* KVth = xt + 8l * 1024 * 1024;
    _Float16* Rth  = xt + 12l * 1024 * 1024;
    _Float16* Wqt  = (_Float16*)(base + 64l * 1024 * 1024);
    _Float16* Wkh  = Wqt + DD;
    _Float16* Wvh  = Wkh + DD;
    float*    xs   = (float*)(Wvh + DD);
    float*    u2   = xs + 4 * 1024;
    float*    w    = u2 + 4 * 1024;
    float*    cv   = w + 4 * 1024;
    _Float16* parts = (_Float16*)d_out;   // [16][1024][1024] fp16 scratch

    // 1) converts / transposes
    cvt_transpose<true ><<<dim3(16, 64, 4), 256, 0, stream>>>(x,  xt,  xh, SEQ, DM);
    cvt_transpose<false><<<dim3(16, 16, 1), 256, 0, stream>>>(Wq, Wqt, nullptr, DM, DM);
    cvt_pair<<<2048, 256, 0, stream>>>(Wk, Wkh, Wv, Wvh);

    // 2) xs = rowsum(xt)
    rowsum_xt<<<1024, 256, 0, stream>>>(xt, xs);

    // 3) u2 = Wv.xs + 4096*bv ; w = Wk.xs
    gemv_dual<<<2048, 256, 0, stream>>>(Wvh, Wkh, xs, bv, u2);

    // 4) Gram split-K=4 (pipelined): parts[b*4+k] = xt-slice @ xt-slice^T
    gemm_big<_Float16, 0><<<512, 512, 0, stream>>>(
        xt, xt, parts, 1024, SEQ, SEQ, DM, 8, 32,
        DS, DS, DD, 4, 1024, 1024, nullptr, 0, 1.0f);

    // 5) Gh = (1/32)*sum parts
    reduce_gh<<<2048, 256, 0, stream>>>(parts, Gh);

    // 6) Ph[b] = Wv . Gh[b]   (G symmetric -> NT)
    gemm64<0><<<1024, 256, 0, stream>>>(
        Wvh, Gh, Ph, 1024, DM, DM, DM, 16, 256,
        0, DD, DD, nullptr, 0, nullptr, 0, nullptr, 0, nullptr, 0, 0.f);

    // 7) KVth[b] = Ph . Wk^T + (1/32)(bk[col]*u2[row] + w[col]*bv[row])
    gemm64<3><<<1024, 256, 0, stream>>>(
        Ph, Wkh, KVth, 1024, DM, DM, DM, 16, 256,
        DD, 0, DD, bk, 0, u2, 1024, w, 1024, bv, 0, 0.03125f);

    // 8) cv[b][e] = sum_d bq[d]*KVth[b][e][d]
    gemv_k1024<<<1024, 256, 0, stream>>>(KVth, DD, bq, cv);

    // 9) Rth[b] = KVth . Wq^T
    gemm64<0><<<1024, 256, 0, stream>>>(
        KVth, Wqt, Rth, 1024, DM, DM, DM, 16, 256,
        DD, 0, DD, nullptr, 0, nullptr, 0, nullptr, 0, nullptr, 0, 0.f);

    // 10) E[b] = xh . Rth^T + cv  (pipelined) -> fp32 out
    gemm_big<float, 1><<<512, 512, 0, stream>>>(
        xh, Rth, out, 1024, DM, DM, DM, 8, 128,
        DS, DD, DS, 1, 0, 0, cv, 1024, 1.0f);
}

// Round 7
// 174.177 us; speedup vs baseline: 1.1610x; 1.1610x over previous
//
#include <hip/hip_runtime.h>
#include <hip/hip_fp16.h>

// EfficientAttention  B=4, S=4096, D=1024, fp32 in/out.
//   G[b]   = x[b]^T x[b]              (Gram, split-K=4, fp16 partials in d_out)
//   Gh     = (1/32) sum_k parts
//   Ph[b]  = Wv Gh[b] ; KVt[b] = Ph Wk^T + rank-1 bias ; Rt[b] = KVt Wq^T
//   E[b]   = x Rt^T + cv[b]
// Big GEMMs (Gram, E): 256x256 8-phase template (T2+T3+T4+T5): 8 waves (2Mx4N),
// BK=64, 2-buffer LDS (128KiB) with retirement-matched half-blocks, one
// half-block staged per phase, counted vmcnt(4) once per K-tile.

#define BATCH 4
#define SEQ   4096
#define DM    1024

typedef _Float16 h8 __attribute__((ext_vector_type(8)));
typedef _Float16 h4 __attribute__((ext_vector_type(4)));
typedef float    f4 __attribute__((ext_vector_type(4)));

__device__ inline void gload_lds16(const _Float16* g, _Float16* l) {
    __builtin_amdgcn_global_load_lds(
        (const __attribute__((address_space(1))) void*)g,
        (__attribute__((address_space(3))) void*)l,
        16, 0, 0);
}

// bijective XCD chunk swizzle (gridDim.x % 8 == 0)
__device__ inline int xcd_swz(int bid, int grid) {
    const int q = grid >> 3;
    return (bid & 7) * q + (bid >> 3);
}

// fp32 [Z][R][C] -> fp16 transposed [Z][C][R] (dstT), optionally also row-major fp16.
template<bool WRITE_RM>
__global__ __launch_bounds__(256) void cvt_transpose(
    const float* __restrict__ src, _Float16* __restrict__ dstT,
    _Float16* __restrict__ dstRM, int R, int C)
{
    __shared__ float tile[64][65];
    const long zoff = (long)blockIdx.z * R * C;
    src += zoff; dstT += zoff;
    if (WRITE_RM) dstRM += zoff;
    const int r0 = blockIdx.y * 64;
    const int c0 = blockIdx.x * 64;
    const int t  = threadIdx.x;
    const int tr = t >> 4;
    const int tc = (t & 15) * 4;
    #pragma unroll
    for (int i = 0; i < 4; ++i) {
        const int r = tr + i * 16;
        f4 v = *(const f4*)&src[(long)(r0 + r) * C + c0 + tc];
        tile[r][tc + 0] = v.x; tile[r][tc + 1] = v.y;
        tile[r][tc + 2] = v.z; tile[r][tc + 3] = v.w;
        if (WRITE_RM) {
            h4 h = { (_Float16)v.x, (_Float16)v.y, (_Float16)v.z, (_Float16)v.w };
            *(h4*)&dstRM[(long)(r0 + r) * C + c0 + tc] = h;
        }
    }
    __syncthreads();
    #pragma unroll
    for (int i = 0; i < 4; ++i) {
        const int c = tr + i * 16;
        h4 h = { (_Float16)tile[tc + 0][c], (_Float16)tile[tc + 1][c],
                 (_Float16)tile[tc + 2][c], (_Float16)tile[tc + 3][c] };
        *(h4*)&dstT[(long)(c0 + c) * R + r0 + tc] = h;
    }
}

// Wk, Wv -> fp16 in one launch
__global__ __launch_bounds__(256) void cvt_pair(
    const float* __restrict__ s0, _Float16* __restrict__ d0,
    const float* __restrict__ s1, _Float16* __restrict__ d1)
{
    const int half = blockIdx.x >> 10;
    const long i = ((long)(blockIdx.x & 1023) * 256 + threadIdx.x) * 4;
    const float* s = half ? s1 : s0;
    _Float16*    d = half ? d1 : d0;
    f4 v = *(const f4*)(s + i);
    h4 h = { (_Float16)v.x, (_Float16)v.y, (_Float16)v.z, (_Float16)v.w };
    *(h4*)(d + i) = h;
}

// xs[b*DM + d] = sum_s xt[b][d][s]
__global__ __launch_bounds__(256) void rowsum_xt(
    const _Float16* __restrict__ xt, float* __restrict__ xs)
{
    const int gw   = blockIdx.x * 4 + (threadIdx.x >> 6);
    const int lane = threadIdx.x & 63;
    const _Float16* row = xt + (long)gw * SEQ;
    float s = 0.f;
    #pragma unroll
    for (int i = 0; i < SEQ; i += 512) {
        h8 v = *(const h8*)&row[i + lane * 8];
        #pragma unroll
        for (int j = 0; j < 8; ++j) s += (float)v[j];
    }
    #pragma unroll
    for (int off = 32; off; off >>= 1) s += __shfl_down(s, off);
    if (lane == 0) xs[gw] = s;
}

// dual gemv: u2 = Wv.xs + S*bv ; w = Wk.xs   (dst = u2 base, 8192 floats)
__global__ __launch_bounds__(256) void gemv_dual(
    const _Float16* __restrict__ Wvh, const _Float16* __restrict__ Wkh,
    const float* __restrict__ xs, const float* __restrict__ bv,
    float* __restrict__ dst)
{
    const int gw   = blockIdx.x * 4 + (threadIdx.x >> 6);
    const int half = gw >> 12;
    const int g    = gw & 4095;
    const int b    = g >> 10;
    const int o    = g & 1023;
    const int lane = threadIdx.x & 63;
    const _Float16* wr = (half ? Wkh : Wvh) + (long)o * 1024;
    const float*    v  = xs + b * 1024;
    float s = 0.f;
    #pragma unroll
    for (int i = 0; i < 2; ++i) {
        const int k = i * 512 + lane * 8;
        h8 wv = *(const h8*)&wr[k];
        f4 v0 = *(const f4*)&v[k];
        f4 v1 = *(const f4*)&v[k + 4];
        s += (float)wv[0] * v0.x + (float)wv[1] * v0.y +
             (float)wv[2] * v0.z + (float)wv[3] * v0.w +
             (float)wv[4] * v1.x + (float)wv[5] * v1.y +
             (float)wv[6] * v1.z + (float)wv[7] * v1.w;
    }
    #pragma unroll
    for (int off = 32; off; off >>= 1) s += __shfl_down(s, off);
    if (lane == 0) dst[gw] = s + (half ? 0.f : (float)SEQ * bv[o]);
}

// out[b*1024+o] = sum_k W[b*wZ + o*1024 + k] * vec[k]
__global__ __launch_bounds__(256) void gemv_k1024(
    const _Float16* __restrict__ W, long wZ,
    const float* __restrict__ vec, float* __restrict__ out)
{
    const int gw   = blockIdx.x * 4 + (threadIdx.x >> 6);
    const int b    = gw >> 10;
    const int o    = gw & 1023;
    const int lane = threadIdx.x & 63;
    const _Float16* wr = W + b * wZ + (long)o * 1024;
    float s = 0.f;
    #pragma unroll
    for (int i = 0; i < 2; ++i) {
        const int k = i * 512 + lane * 8;
        h8 wv = *(const h8*)&wr[k];
        f4 v0 = *(const f4*)&vec[k];
        f4 v1 = *(const f4*)&vec[k + 4];
        s += (float)wv[0] * v0.x + (float)wv[1] * v0.y +
             (float)wv[2] * v0.z + (float)wv[3] * v0.w +
             (float)wv[4] * v1.x + (float)wv[5] * v1.y +
             (float)wv[6] * v1.z + (float)wv[7] * v1.w;
    }
    #pragma unroll
    for (int off = 32; off; off >>= 1) s += __shfl_down(s, off);
    if (lane == 0) out[gw] = s;
}

// Gh = (1/32) * sum_{k<4} parts (fp16 partials)
__global__ __launch_bounds__(256) void reduce_gh(
    const _Float16* __restrict__ parts, _Float16* __restrict__ Gh)
{
    const long DD_ = (long)DM * DM;
    const long i = ((long)blockIdx.x * 256 + threadIdx.x) * 8;
    const long b = i >> 20;
    const long r = i & (DD_ - 1);
    const _Float16* p = parts + b * 4 * DD_ + r;
    h8 v0 = *(const h8*)&p[0];
    h8 v1 = *(const h8*)&p[DD_];
    h8 v2 = *(const h8*)&p[2 * DD_];
    h8 v3 = *(const h8*)&p[3 * DD_];
    h8 o;
    #pragma unroll
    for (int j = 0; j < 8; ++j) {
        float s = (float)v0[j] + (float)v1[j] + (float)v2[j] + (float)v3[j];
        o[j] = (_Float16)(s * 0.03125f);
    }
    *(h8*)&Gh[i] = o;
}

// ---------------------------------------------------------------------------
// 8-phase 256x256 NT GEMM (T2+T3+T4+T5).
// 512 thr = 8 waves (2M x 4N); wave output 128x64 = acc[8][4] 16x16 frags.
// LDS per buffer: A half-blocks A[mq] (mq=0,1: the 64-row group of each wave-M
// half read only in phases with that mq) + B half-blocks B[nq]. 16 KB each,
// 2 buffers = 128 KiB. One half-block (2 gloads/thread) staged per phase:
//   p1:(j+1)A1  p2:(j+1)B1  p3:(j+2)A0  p4:(j+2)B0
// Each stage lands in a region whose last reader finished >=1 barrier earlier.
// Counted vmcnt(4) once per K-tile (before p4 closing barrier): all of tile
// j+1 landed, (j+2) A0/B0 (4 loads) stay in flight.
// A-frags register-cached across (p1,p2); B-frags cached across the K-tile.
// ---------------------------------------------------------------------------
template<typename OutT, int BIAS>
__global__ __launch_bounds__(512, 1) void gemm8p(
    const _Float16* __restrict__ A, const _Float16* __restrict__ B,
    OutT* __restrict__ C,
    int K, int lda, int ldb, int ldc, int tilesX, int perZ,
    long aZ, long bZ, long cZ, int sk, long aK, long bK,
    const float* __restrict__ bc1, long bc1Z, float alpha)
{
    __shared__ _Float16 lds[2 * 32768];   // 128 KiB

    const int L  = xcd_swz(blockIdx.x, gridDim.x);
    const int z  = L / perZ;
    const int r0 = L - z * perZ;
    const int zb = z / sk;
    const int zk = z - zb * sk;
    A += (long)zb * aZ + (long)zk * aK;
    B += (long)zb * bZ + (long)zk * bK;
    C += (long)z * cZ;
    const float* pc1 = (BIAS == 1) ? bc1 + (long)zb * bc1Z : nullptr;

    const int tileM = (r0 / tilesX) * 256;
    const int tileN = (r0 % tilesX) * 256;
    const int tid   = threadIdx.x;
    const int lane  = tid & 63;
    const int wave  = tid >> 6;
    const int wr    = wave >> 2;          // 0..1  (M half)
    const int wc    = wave & 3;           // 0..3  (N quarter)
    const int la    = lane & 15;
    const int kg    = lane >> 4;

    // stage helpers: linear LDS dest (required by global_load_lds), inverse
    // swizzle on the global source column group (both-sides rule).
    auto stageA = [&](int buf, int mq, int kt) {
        _Float16* dst = &lds[buf * 32768 + mq * 8192];
        const int k0 = kt * 64;
        #pragma unroll
        for (int i = 0; i < 2; ++i) {
            const int U = i * 512 + tid;
            const int R = U >> 3, s = U & 7;
            const int gr = tileM + (R >> 6) * 128 + mq * 64 + (R & 63);
            gload_lds16(&A[(long)gr * lda + k0 + ((s ^ (R & 7)) << 3)], dst + U * 8);
        }
    };
    auto stageB = [&](int buf, int nq, int kt) {
        _Float16* dst = &lds[buf * 32768 + 16384 + nq * 8192];
        const int k0 = kt * 64;
        #pragma unroll
        for (int i = 0; i < 2; ++i) {
            const int U = i * 512 + tid;
            const int R = U >> 3, s = U & 7;
            const int gn = tileN + (R >> 5) * 64 + nq * 32 + (R & 31);
            gload_lds16(&B[(long)gn * ldb + k0 + ((s ^ (R & 7)) << 3)], dst + U * 8);
        }
    };

    f4 acc[8][4] = {};
    h8 af[4][2];        // A frags for current mq (read at p1 / p3)
    h8 bf[2][2][2];     // bf[nq][ni][kk], cached across the K-tile

    auto readA = [&](int buf, int mq) {
        const _Float16* Ab = &lds[buf * 32768 + mq * 8192];
        #pragma unroll
        for (int mi = 0; mi < 4; ++mi)
            #pragma unroll
            for (int kk = 0; kk < 2; ++kk) {
                const int R = wr * 64 + mi * 16 + la;
                const int s = kk * 4 + kg;
                af[mi][kk] = *(const h8*)&Ab[R * 64 + ((s ^ (R & 7)) << 3)];
            }
    };
    auto readB = [&](int buf, int nq) {
        const _Float16* Bb = &lds[buf * 32768 + 16384 + nq * 8192];
        #pragma unroll
        for (int ni = 0; ni < 2; ++ni)
            #pragma unroll
            for (int kk = 0; kk < 2; ++kk) {
                const int R = wc * 32 + ni * 16 + la;
                const int s = kk * 4 + kg;
                bf[nq][ni][kk] = *(const h8*)&Bb[R * 64 + ((s ^ (R & 7)) << 3)];
            }
    };
    auto mfmaQ = [&](int mq, int nq) {
        __builtin_amdgcn_s_setprio(1);
        #pragma unroll
        for (int mi = 0; mi < 4; ++mi)
            #pragma unroll
            for (int ni = 0; ni < 2; ++ni)
                #pragma unroll
                for (int kk = 0; kk < 2; ++kk)
                    acc[mq * 4 + mi][nq * 2 + ni] =
                        __builtin_amdgcn_mfma_f32_16x16x32_f16(
                            af[mi][kk], bf[nq][ni][kk],
                            acc[mq * 4 + mi][nq * 2 + ni], 0, 0, 0);
        __builtin_amdgcn_s_setprio(0);
    };

    const int NT = K >> 6;

    // prologue: tile0 fully + tile1 A0/B0; enter steady state (4 in flight)
    stageA(0, 0, 0); stageA(0, 1, 0); stageB(0, 0, 0); stageB(0, 1, 0);
    if (NT > 1) {
        stageA(1, 0, 1); stageB(1, 0, 1);
        asm volatile("s_waitcnt vmcnt(4)" ::: "memory");
    } else {
        asm volatile("s_waitcnt vmcnt(0)" ::: "memory");
    }
    __builtin_amdgcn_sched_barrier(0);
    __builtin_amdgcn_s_barrier();

    for (int j = 0; j < NT; ++j) {
        const int buf = j & 1;
        // P1: mq0 nq0
        readA(buf, 0); readB(buf, 0);
        if (j + 1 < NT) stageA(buf ^ 1, 1, j + 1);
        __builtin_amdgcn_s_barrier();
        mfmaQ(0, 0);
        __builtin_amdgcn_s_barrier();
        // P2: mq0 nq1
        readB(buf, 1);
        if (j + 1 < NT) stageB(buf ^ 1, 1, j + 1);
        __builtin_amdgcn_s_barrier();
        mfmaQ(0, 1);
        __builtin_amdgcn_s_barrier();
        // P3: mq1 nq0
        readA(buf, 1);
        if (j + 2 < NT) stageA(buf, 0, j + 2);
        __builtin_amdgcn_s_barrier();
        mfmaQ(1, 0);
        __builtin_amdgcn_s_barrier();
        // P4: mq1 nq1 + boundary vmcnt
        if (j + 2 < NT) stageB(buf, 0, j + 2);
        __builtin_amdgcn_s_barrier();
        mfmaQ(1, 1);
        if (j + 2 < NT) {
            asm volatile("s_waitcnt vmcnt(4)" ::: "memory");
        } else if (j + 1 < NT) {
            asm volatile("s_waitcnt vmcnt(0)" ::: "memory");
        }
        __builtin_amdgcn_sched_barrier(0);
        __builtin_amdgcn_s_barrier();
    }

    #pragma unroll
    for (int mf = 0; mf < 8; ++mf) {
        #pragma unroll
        for (int nf = 0; nf < 4; ++nf) {
            const int col = tileN + wc * 64 + nf * 16 + la;
            #pragma unroll
            for (int jj = 0; jj < 4; ++jj) {
                const int row = tileM + wr * 128 + mf * 16 + kg * 4 + jj;
                float v = acc[mf][nf][jj] * alpha;
                if (BIAS == 1) v += pc1[col];
                C[(long)row * ldc + col] = (OutT)v;
            }
        }
    }
}

// 64x64 NT GEMM for the 1024^3 chain.
// BIAS: 0 none; 3: + beta*(bc1[col]*br1[row] + bc2[col]*br2[row])
template<int BIAS>
__global__ __launch_bounds__(256) void gemm64(
    const _Float16* __restrict__ A, const _Float16* __restrict__ B,
    _Float16* __restrict__ C,
    int K, int lda, int ldb, int ldc, int tilesX, int perZ,
    long aZ, long bZ, long cZ,
    const float* __restrict__ bc1, long bc1Z,
    const float* __restrict__ br1, long br1Z,
    const float* __restrict__ bc2, long bc2Z,
    const float* __restrict__ br2, long br2Z,
    float beta)
{
    __shared__ _Float16 As[64 * 64];
    __shared__ _Float16 Bs[64 * 64];

    const int L  = xcd_swz(blockIdx.x, gridDim.x);
    const int z  = L / perZ;
    const int r0 = L - z * perZ;
    A += (long)z * aZ;
    B += (long)z * bZ;
    C += (long)z * cZ;
    const float* pc1 = nullptr; const float* pr1 = nullptr;
    const float* pc2 = nullptr; const float* pr2 = nullptr;
    if (BIAS == 3) {
        pc1 = bc1 + (long)z * bc1Z; pr1 = br1 + (long)z * br1Z;
        pc2 = bc2 + (long)z * bc2Z; pr2 = br2 + (long)z * br2Z;
    }

    const int tileM = (r0 / tilesX) * 64;
    const int tileN = (r0 % tilesX) * 64;
    const int tid   = threadIdx.x;
    const int lane  = tid & 63;
    const int wave  = tid >> 6;
    const int wm    = (wave >> 1) * 32;
    const int wn    = (wave & 1) * 32;
    const int srow  = tid >> 3;
    const int sslot = tid & 7;

    f4 acc[2][2] = {};
    const int arow = lane & 15;
    const int kg   = lane >> 4;

    for (int k0 = 0; k0 < K; k0 += 64) {
        #pragma unroll
        for (int i = 0; i < 2; ++i) {
            const int row   = i * 32 + srow;
            const int gslot = sslot ^ (row & 7);
            gload_lds16(&A[(long)(tileM + row) * lda + k0 + gslot * 8],
                        &As[row * 64 + sslot * 8]);
            gload_lds16(&B[(long)(tileN + row) * ldb + k0 + gslot * 8],
                        &Bs[row * 64 + sslot * 8]);
        }
        __syncthreads();

        #pragma unroll
        for (int kk = 0; kk < 64; kk += 32) {
            h8 af[2], bf[2];
            #pragma unroll
            for (int m = 0; m < 2; ++m) {
                const int rr   = wm + m * 16 + arow;
                const int slot = (kk >> 3) + kg;
                af[m] = *(const h8*)&As[rr * 64 + ((slot ^ (rr & 7)) << 3)];
            }
            #pragma unroll
            for (int n = 0; n < 2; ++n) {
                const int rr   = wn + n * 16 + arow;
                const int slot = (kk >> 3) + kg;
                bf[n] = *(const h8*)&Bs[rr * 64 + ((slot ^ (rr & 7)) << 3)];
            }
            #pragma unroll
            for (int m = 0; m < 2; ++m)
                #pragma unroll
                for (int n = 0; n < 2; ++n)
                    acc[m][n] = __builtin_amdgcn_mfma_f32_16x16x32_f16(
                        af[m], bf[n], acc[m][n], 0, 0, 0);
        }
        __syncthreads();
    }

    #pragma unroll
    for (int m = 0; m < 2; ++m) {
        #pragma unroll
        for (int n = 0; n < 2; ++n) {
            const int col = tileN + wn + n * 16 + arow;
            #pragma unroll
            for (int j = 0; j < 4; ++j) {
                const int row = tileM + wm + m * 16 + (lane >> 4) * 4 + j;
                float v = acc[m][n][j];
                if (BIAS == 3) v += beta * (pc1[col] * pr1[row] + pc2[col] * pr2[row]);
                C[(long)row * ldc + col] = (_Float16)v;
            }
        }
    }
}

extern "C" void kernel_launch(void* const* d_in, const int* in_sizes, int n_in,
                              void* d_out, int out_size, void* d_ws, size_t ws_size,
                              hipStream_t stream)
{
    const float* x  = (const float*)d_in[0];
    const float* Wq = (const float*)d_in[1];
    const float* bq = (const float*)d_in[2];
    const float* Wk = (const float*)d_in[3];
    const float* bk = (const float*)d_in[4];
    const float* Wv = (const float*)d_in[5];
    const float* bv = (const float*)d_in[6];
    float* out = (float*)d_out;

    const long DD = (long)DM * DM;
    const long DS = (long)DM * SEQ;

    char* base = (char*)d_ws;
    _Float16* xh   = (_Float16*)base;
    _Float16* xt   = (_Float16*)(base + 32l * 1024 * 1024);
    _Float16* Gh   = xt;
    _Float16* Ph   = xt + 4l * 1024 * 1024;
    _Float16* KVth = xt + 8l * 1024 * 1024;
    _Float16* Rth  = xt + 12l * 1024 * 1024;
    _Float16* Wqt  = (_Float16*)(base + 64l * 1024 * 1024);
    _Float16* Wkh  = Wqt + DD;
    _Float16* Wvh  = Wkh + DD;
    float*    xs   = (float*)(Wvh + DD);
    float*    u2   = xs + 4 * 1024;
    float*    w    = u2 + 4 * 1024;
    float*    cv   = w + 4 * 1024;
    _Float16* parts = (_Float16*)d_out;   // [16][1024][1024] fp16 scratch

    // 1) converts / transposes
    cvt_transpose<true ><<<dim3(16, 64, 4), 256, 0, stream>>>(x,  xt,  xh, SEQ, DM);
    cvt_transpose<false><<<dim3(16, 16, 1), 256, 0, stream>>>(Wq, Wqt, nullptr, DM, DM);
    cvt_pair<<<2048, 256, 0, stream>>>(Wk, Wkh, Wv, Wvh);

    // 2) xs = rowsum(xt)
    rowsum_xt<<<1024, 256, 0, stream>>>(xt, xs);

    // 3) u2 = Wv.xs + 4096*bv ; w = Wk.xs
    gemv_dual<<<2048, 256, 0, stream>>>(Wvh, Wkh, xs, bv, u2);

    // 4) Gram split-K=4 (8-phase): parts[b*4+k] = xt-slice @ xt-slice^T
    gemm8p<_Float16, 0><<<256, 512, 0, stream>>>(
        xt, xt, parts, 1024, SEQ, SEQ, DM, 4, 16,
        DS, DS, DD, 4, 1024, 1024, nullptr, 0, 1.0f);

    // 5) Gh = (1/32)*sum parts
    reduce_gh<<<2048, 256, 0, stream>>>(parts, Gh);

    // 6) Ph[b] = Wv . Gh[b]   (G symmetric -> NT)
    gemm64<0><<<1024, 256, 0, stream>>>(
        Wvh, Gh, Ph, 1024, DM, DM, DM, 16, 256,
        0, DD, DD, nullptr, 0, nullptr, 0, nullptr, 0, nullptr, 0, 0.f);

    // 7) KVth[b] = Ph . Wk^T + (1/32)(bk[col]*u2[row] + w[col]*bv[row])
    gemm64<3><<<1024, 256, 0, stream>>>(
        Ph, Wkh, KVth, 1024, DM, DM, DM, 16, 256,
        DD, 0, DD, bk, 0, u2, 1024, w, 1024, bv, 0, 0.03125f);

    // 8) cv[b][e] = sum_d bq[d]*KVth[b][e][d]
    gemv_k1024<<<1024, 256, 0, stream>>>(KVth, DD, bq, cv);

    // 9) Rth[b] = KVth . Wq^T
    gemm64<0><<<1024, 256, 0, stream>>>(
        KVth, Wqt, Rth, 1024, DM, DM, DM, 16, 256,
        DD, 0, DD, nullptr, 0, nullptr, 0, nullptr, 0, nullptr, 0, 0.f);

    // 10) E[b] = xh . Rth^T + cv  (8-phase) -> fp32 out
    gemm8p<float, 1><<<256, 512, 0, stream>>>(
        xh, Rth, out, 1024, DM, DM, DM, 4, 64,
        DS, DD, DS, 1, 0, 0, cv, 1024, 1.0f);
}